// Round 10
// baseline (337.147 us; speedup 1.0000x reference)
//
#include <hip/hip_runtime.h>

#define T_LEN 256
#define D_IN 4
#define HID 16
#define NTHREADS 384

typedef _Float16 half8 __attribute__((ext_vector_type(8)));
typedef __fp16 cvt2_t __attribute__((ext_vector_type(2)));
typedef float float4v __attribute__((ext_vector_type(4)));

struct CellW { const float *Wih, *Whh, *bih, *bhh; };
struct Params { CellW c[6]; const float* y; float* hout; };

__device__ __forceinline__ float fexp2(float x) { return __builtin_amdgcn_exp2f(x); }
__device__ __forceinline__ float frcp(float x)  { return __builtin_amdgcn_rcpf(x); }
__device__ __forceinline__ int packh(float a, float b) {
    cvt2_t p = __builtin_amdgcn_cvt_pkrtz(a, b);
    return __builtin_bit_cast(int, p);
}

#define MFMA(a, b, c) __builtin_amdgcn_mfma_f32_16x16x32_f16(a, b, c, 0, 0, 0)

// One unit-batch LSTM update, paired-rcp form: 5 exp + 3 rcp (vs 10 naive).
// pi,pf,po pre-scaled by -log2e; pg by -2log2e (folded into A/bias).
// i = 1/(1+ei); g = (1-eg)/(1+eg); i*g = (1-eg)*rcp((1+ei)(1+eg)).
// h = o*tanh(c) = (1-ec)*rcp((1+eo)(1+ec)).  Clamp exps at 2^40 (inf-safe,
// correct limits, error ~1e-12).
__device__ __forceinline__ float act_one(float pi, float pf, float pg, float po,
                                         float& c) {
    float ei = fexp2(fminf(pi, 40.f));
    float ef = fexp2(pf);
    float eg = fexp2(fminf(pg, 40.f));
    float f  = frcp(1.f + ef);
    float ig = (1.f - eg) * frcp((1.f + ei) * (1.f + eg));
    float cn = fmaf(f, c, ig);
    c = cn;
    float eo = fexp2(fminf(po, 40.f));
    float ec = fexp2(fminf(cn * -2.8853900817779268f, 40.f));
    return (1.f - ec) * frcp((1.f + eo) * (1.f + ec));
}

// Block = 6 waves = 3 layers x 2 unit-halves of one 16-chain tile.
// Layers skewed by 1 round; h crosses waves via parity-buffered LDS slabs;
// x fully preloaded. Each half-wave issues all 4 gate MFMAs (redundant,
// cheap) but activates only D-regs {2u, 2u+1} -> half the trans ops.
__global__ void __launch_bounds__(NTHREADS)
lstm_chain_kernel(Params p)
{
    __shared__ int lds_x[16 * 516];            // [chain][t] fp16-pair; +4 pad
    __shared__ _Float16 lds_h[3][2][16][24];   // [layer][parity][batch][unit+pad]

    const int wv = threadIdx.x >> 6;   // 0..5
    const int w  = wv >> 1;            // layer
    const int u  = wv & 1;             // unit-half: D regs 2u, 2u+1
    const int L  = threadIdx.x & 63;
    const int n  = L & 15;             // batch col
    const int Q  = L >> 4;

    const int tid = blockIdx.x;
    const int dir = tid & 1;
    const int b0  = (tid >> 1) * 16;

    const CellW cw = p.c[dir * 3 + w];
    const float LOG2E = 1.4426950408889634f;

    // ---- A-frags + bias for this layer (scale folded) ----
    half8 A[4];
    float4v bs[4];
#pragma unroll
    for (int g = 0; g < 4; ++g) {
        const float s = (g == 2) ? -2.f * LOG2E : -LOG2E;
        const int row = g * 16 + n;
        half8 a;
#pragma unroll
        for (int j = 0; j < 8; ++j) {
            int k = Q * 8 + j;
            float v;
            if (w == 0) {
                if (k < D_IN)    v = cw.Wih[row * D_IN + k];
                else if (k < 16) v = 0.f;
                else             v = cw.Whh[row * 16 + (k - 16)];
            } else {
                v = (k < 16) ? cw.Wih[row * 16 + k] : cw.Whh[row * 16 + (k - 16)];
            }
            a[j] = (_Float16)(v * s);
        }
        A[g] = a;
        const int u0 = g * 16 + 4 * Q;
        float4 bi = *(const float4*)&cw.bih[u0];
        float4 bh = *(const float4*)&cw.bhh[u0];
        bs[g] = (float4v){(bi.x+bh.x)*s, (bi.y+bh.y)*s, (bi.z+bh.z)*s, (bi.w+bh.w)*s};
    }

    // ---- preload x (t-inner: coalesced global, 2-way-free LDS stores) ----
    {
        const float* ybase = p.y + (size_t)b0 * (T_LEN * D_IN);
        for (int idx = threadIdx.x; idx < 16 * T_LEN; idx += NTHREADS) {
            const int c = idx >> 8, t = idx & 255;
            const int tt = dir ? (T_LEN - 1 - t) : t;
            float4 v = *(const float4*)(ybase + ((size_t)c * T_LEN + tt) * D_IN);
            lds_x[c * 516 + 2 * t]     = packh(v.x, v.y);
            lds_x[c * 516 + 2 * t + 1] = packh(v.z, v.w);
        }
        for (int idx = threadIdx.x; idx < 3 * 2 * 16 * 12; idx += NTHREADS)
            ((int*)lds_h)[idx] = 0;
    }
    __syncthreads();

    float cst0 = 0.f, cst1 = 0.f;
    float hl0 = 0.f, hl1 = 0.f;
    const int r0 = 2 * u, r1 = 2 * u + 1;

#pragma unroll 1
    for (int s = 0; s < T_LEN + 2; ++s) {
        const int t = s - w;
        if (t >= 0 && t < T_LEN) {
            int bd0 = 0, bd1 = 0, bd2 = 0, bd3 = 0;
            if (w == 0) {
                if (Q == 0) {
                    int2 xv = *(const int2*)&lds_x[n * 516 + 2 * t];
                    bd0 = xv.x; bd1 = xv.y;
                } else if (Q >= 2) {
                    int4 hv = *(const int4*)&lds_h[0][(s + 1) & 1][n][(Q & 1) * 8];
                    bd0 = hv.x; bd1 = hv.y; bd2 = hv.z; bd3 = hv.w;
                }
            } else {
                const int slab = (Q < 2) ? (w - 1) : w;
                int4 hv = *(const int4*)&lds_h[slab][(s + 1) & 1][n][(Q & 1) * 8];
                bd0 = hv.x; bd1 = hv.y; bd2 = hv.z; bd3 = hv.w;
            }
            int4 bi4 = {bd0, bd1, bd2, bd3};
            half8 b = __builtin_bit_cast(half8, bi4);
            float4v pi = MFMA(A[0], b, bs[0]);
            float4v pf = MFMA(A[1], b, bs[1]);
            float4v pg = MFMA(A[2], b, bs[2]);
            float4v po = MFMA(A[3], b, bs[3]);
            hl0 = act_one(pi[r0], pf[r0], pg[r0], po[r0], cst0);
            hl1 = act_one(pi[r1], pf[r1], pg[r1], po[r1], cst1);
            // units 4Q+2u, 4Q+2u+1 for batch n (one dword, 48B rows: <=2-way)
            *(int*)&lds_h[w][s & 1][n][4 * Q + 2 * u] = packh(hl0, hl1);
        }
        __syncthreads();
    }

    // layer-2 waves hold h3(T-1): units 4Q+2u..+1, batch n
    if (w == 2) {
        float2 hv = {hl0, hl1};
        *(float2*)&p.hout[(size_t)(b0 + n) * 32 + dir * HID + 4 * Q + 2 * u] = hv;
    }
}

__global__ void out_proj_kernel(const float* __restrict__ ws,
                                const float* __restrict__ Wout,
                                const float* __restrict__ bout,
                                float* __restrict__ out, int B)
{
    int idx = blockIdx.x * blockDim.x + threadIdx.x;
    if (idx >= B * 4) return;
    int b = idx >> 2, o = idx & 3;
    float acc = bout[o];
    const float* h = ws + (size_t)b * 32;
    const float* w = Wout + o * 32;
#pragma unroll
    for (int m = 0; m < 32; ++m) acc = fmaf(h[m], w[m], acc);
    out[idx] = acc;
}

extern "C" void kernel_launch(void* const* d_in, const int* in_sizes, int n_in,
                              void* d_out, int out_size, void* d_ws, size_t ws_size,
                              hipStream_t stream)
{
    const int B = in_sizes[0] / (T_LEN * D_IN); // 4096

    Params p;
    for (int s = 0; s < 6; ++s) {
        p.c[s].Wih = (const float*)d_in[1 + 4 * s];
        p.c[s].Whh = (const float*)d_in[2 + 4 * s];
        p.c[s].bih = (const float*)d_in[3 + 4 * s];
        p.c[s].bhh = (const float*)d_in[4 + 4 * s];
    }
    p.y = (const float*)d_in[0];
    p.hout = (float*)d_ws;

    const int tiles = (B / 16) * 2;          // 16 chains per tile, both dirs
    lstm_chain_kernel<<<tiles, NTHREADS, 0, stream>>>(p);

    const float* Wout = (const float*)d_in[25];
    const float* bout = (const float*)d_in[26];
    out_proj_kernel<<<(B * 4 + 255) / 256, 256, 0, stream>>>(
        (const float*)d_ws, Wout, bout, (float*)d_out, B);
}

// Round 12
// 292.758 us; speedup vs baseline: 1.1516x; 1.1516x over previous
//
#include <hip/hip_runtime.h>

#define T_LEN 256
#define D_IN 4
#define HID 16
#define SPR 4                       // timesteps per barrier round
#define NROUND (T_LEN / SPR + 2)    // 66: layer skew 0..2

typedef _Float16 half8 __attribute__((ext_vector_type(8)));
typedef __fp16 cvt2_t __attribute__((ext_vector_type(2)));
typedef float float4v __attribute__((ext_vector_type(4)));

struct CellW { const float *Wih, *Whh, *bih, *bhh; };
struct Params { CellW c[6]; const float* y; float* hout; };

__device__ __forceinline__ float fexp2(float x) { return __builtin_amdgcn_exp2f(x); }
__device__ __forceinline__ float frcp(float x)  { return __builtin_amdgcn_rcpf(x); }
__device__ __forceinline__ int bperm(int a, int v) { return __builtin_amdgcn_ds_bpermute(a, v); }
__device__ __forceinline__ int packh(float a, float b) {
    cvt2_t p = __builtin_amdgcn_cvt_pkrtz(a, b);
    return __builtin_bit_cast(int, p);
}

#define MFMA(a, b, c) __builtin_amdgcn_mfma_f32_16x16x32_f16(a, b, c, 0, 0, 0)

// Paired-rcp LSTM activation: 5 exp + 3 rcp. pi,pf,po pre-scaled by -log2e,
// pg by -2log2e (folded into A/bias). Only ec needs a clamp (c can grow; the
// (1-ec)*rcp(..*(1+ec)) form would give inf*0=NaN). Other preacts are bounded
// by |b|+0.25*(sum|h|+sum|x|) < ~14 -> exp2 args < ~40, no overflow.
__device__ __forceinline__ float act_one(float pi, float pf, float pg, float po,
                                         float& c) {
    float ei = fexp2(pi);
    float ef = fexp2(pf);
    float eg = fexp2(pg);
    float f  = frcp(1.f + ef);
    float ig = (1.f - eg) * frcp((1.f + ei) * (1.f + eg));
    float cn = fmaf(f, c, ig);
    c = cn;
    float eo = fexp2(po);
    float ec = fexp2(fminf(cn * -2.8853900817779268f, 80.f));
    return (1.f - ec) * frcp((1.f + eo) * (1.f + ec));
}

// Block = 3 waves = 3 layers of one 16-chain tile. Each barrier round does
// SPR timesteps; cross-layer h via parity LDS slabs, own recurrence via
// in-register bpermute (round-8 verified mapping). 66 barriers total.
__global__ void __launch_bounds__(192)
lstm_chain_kernel(Params p)
{
    __shared__ _Float16 lds_h[2][2][SPR][16][24];   // [prod][parity][k][batch][unit+pad] 12KB

    const int w = threadIdx.x >> 6;     // wave = layer
    const int L = threadIdx.x & 63;
    const int n = L & 15;               // batch col
    const int Q = L >> 4;

    const int tid = blockIdx.x;
    const int dir = tid & 1;
    const int b0  = (tid >> 1) * 16;

    const CellW cw = p.c[dir * 3 + w];
    const float LOG2E = 1.4426950408889634f;

    // ---- A-frags + bias for this layer (activation scale folded) ----
    half8 A[4];
    float4v bs[4];
#pragma unroll
    for (int g = 0; g < 4; ++g) {
        const float s = (g == 2) ? -2.f * LOG2E : -LOG2E;
        const int row = g * 16 + n;
        half8 a;
#pragma unroll
        for (int j = 0; j < 8; ++j) {
            int k = Q * 8 + j;
            float v;
            if (w == 0) {
                if (k < D_IN)    v = cw.Wih[row * D_IN + k];
                else if (k < 16) v = 0.f;
                else             v = cw.Whh[row * 16 + (k - 16)];
            } else {
                v = (k < 16) ? cw.Wih[row * 16 + k] : cw.Whh[row * 16 + (k - 16)];
            }
            a[j] = (_Float16)(v * s);
        }
        A[g] = a;
        const int u0 = g * 16 + 4 * Q;
        float4 bi = *(const float4*)&cw.bih[u0];
        float4 bh = *(const float4*)&cw.bhh[u0];
        bs[g] = (float4v){(bi.x+bh.x)*s, (bi.y+bh.y)*s, (bi.z+bh.z)*s, (bi.w+bh.w)*s};
    }

    // own-recurrence bpermute addresses (round-8 verified)
    const int aL = 4 * ((Q & 1) * 32 + n);
    const int aH = aL + 64;

    // ---- x prefetch state (wave 0, Q==0 lanes only) ----
    const float* ybase = p.y + (size_t)b0 * (T_LEN * D_IN);
    float4 xn[SPR];
    int xp[SPR][2];
    if (w == 0 && Q == 0) {
#pragma unroll
        for (int k = 0; k < SPR; ++k) {
            const int tt = dir ? (T_LEN - 1 - k) : k;
            xn[k] = *(const float4*)(ybase + ((size_t)n * T_LEN + tt) * D_IN);
        }
    }

    float cc[4] = {0.f, 0.f, 0.f, 0.f};
    float h[4] = {0.f, 0.f, 0.f, 0.f};
    int g4[4] = {0, 0, 0, 0};

#pragma unroll 1
    for (int s = 0; s < NROUND; ++s) {
        __syncthreads();
        const int t0 = (s - w) * SPR;
        if (t0 < 0 || t0 >= T_LEN) continue;

        // wave 0: commit prefetched x, start next round's loads
        if (w == 0 && Q == 0) {
#pragma unroll
            for (int k = 0; k < SPR; ++k) {
                xp[k][0] = packh(xn[k].x, xn[k].y);
                xp[k][1] = packh(xn[k].z, xn[k].w);
            }
            if (t0 + SPR < T_LEN) {
#pragma unroll
                for (int k = 0; k < SPR; ++k) {
                    const int t = t0 + SPR + k;
                    const int tt = dir ? (T_LEN - 1 - t) : t;
                    xn[k] = *(const float4*)(ybase + ((size_t)n * T_LEN + tt) * D_IN);
                }
            }
        }

        // hoist all cross-layer h reads (independent of in-round compute)
        int4 hv[SPR];
        if (w >= 1 && Q < 2) {
#pragma unroll
            for (int k = 0; k < SPR; ++k)
                hv[k] = *(const int4*)&lds_h[w - 1][(s + 1) & 1][k][n][(Q & 1) * 8];
        }

#pragma unroll
        for (int k = 0; k < SPR; ++k) {
            int bd0, bd1, bd2, bd3;
            if (Q >= 2) {                       // own h(t-1), in-register
                bd0 = g4[0]; bd1 = g4[1]; bd2 = g4[2]; bd3 = g4[3];
            } else if (w == 0) {
                if (Q == 0) { bd0 = xp[k][0]; bd1 = xp[k][1]; bd2 = 0; bd3 = 0; }
                else        { bd0 = 0; bd1 = 0; bd2 = 0; bd3 = 0; }
            } else {                            // prev-layer h(t)
                bd0 = hv[k].x; bd1 = hv[k].y; bd2 = hv[k].z; bd3 = hv[k].w;
            }
            int4 bi4 = {bd0, bd1, bd2, bd3};
            half8 b = __builtin_bit_cast(half8, bi4);
            float4v pi = MFMA(A[0], b, bs[0]);
            float4v pf = MFMA(A[1], b, bs[1]);
            float4v pg = MFMA(A[2], b, bs[2]);
            float4v po = MFMA(A[3], b, bs[3]);
            h[0] = act_one(pi[0], pf[0], pg[0], po[0], cc[0]);
            h[1] = act_one(pi[1], pf[1], pg[1], po[1], cc[1]);
            h[2] = act_one(pi[2], pf[2], pg[2], po[2], cc[2]);
            h[3] = act_one(pi[3], pf[3], pg[3], po[3], cc[3]);
            const int d0 = packh(h[0], h[1]);
            const int d1 = packh(h[2], h[3]);
            g4[0] = bperm(aL, d0);
            g4[1] = bperm(aL, d1);
            g4[2] = bperm(aH, d0);
            g4[3] = bperm(aH, d1);
            if (w < 2) {
                int2 hw = {d0, d1};
                *(int2*)&lds_h[w][s & 1][k][n][4 * Q] = hw;   // units 4Q..4Q+3
            }
        }
    }

    // wave 2 holds h3(T-1): lane (n,Q) has units 4Q..4Q+3, batch n
    if (w == 2) {
        float4v ho = {h[0], h[1], h[2], h[3]};
        *(float4v*)&p.hout[(size_t)(b0 + n) * 32 + dir * HID + 4 * Q] = ho;
    }
}

__global__ void out_proj_kernel(const float* __restrict__ ws,
                                const float* __restrict__ Wout,
                                const float* __restrict__ bout,
                                float* __restrict__ out, int B)
{
    int idx = blockIdx.x * blockDim.x + threadIdx.x;
    if (idx >= B * 4) return;
    int b = idx >> 2, o = idx & 3;
    float acc = bout[o];
    const float* h = ws + (size_t)b * 32;
    const float* w = Wout + o * 32;
#pragma unroll
    for (int m = 0; m < 32; ++m) acc = fmaf(h[m], w[m], acc);
    out[idx] = acc;
}

extern "C" void kernel_launch(void* const* d_in, const int* in_sizes, int n_in,
                              void* d_out, int out_size, void* d_ws, size_t ws_size,
                              hipStream_t stream)
{
    const int B = in_sizes[0] / (T_LEN * D_IN); // 4096

    Params p;
    for (int s = 0; s < 6; ++s) {
        p.c[s].Wih = (const float*)d_in[1 + 4 * s];
        p.c[s].Whh = (const float*)d_in[2 + 4 * s];
        p.c[s].bih = (const float*)d_in[3 + 4 * s];
        p.c[s].bhh = (const float*)d_in[4 + 4 * s];
    }
    p.y = (const float*)d_in[0];
    p.hout = (float*)d_ws;

    const int tiles = (B / 16) * 2;          // 16 chains per tile, both dirs
    lstm_chain_kernel<<<tiles, 192, 0, stream>>>(p);

    const float* Wout = (const float*)d_in[25];
    const float* bout = (const float*)d_in[26];
    out_proj_kernel<<<(B * 4 + 255) / 256, 256, 0, stream>>>(
        (const float*)d_ws, Wout, bout, (float*)d_out, B);
}

// Round 13
// 290.249 us; speedup vs baseline: 1.1616x; 1.0086x over previous
//
#include <hip/hip_runtime.h>

#define T_LEN 256
#define D_IN 4
#define SPR 8                       // timesteps per barrier round
#define NROUND (T_LEN / SPR + 2)    // 34: layer skew 0..2

typedef __fp16 h4 __attribute__((ext_vector_type(4)));
typedef __fp16 cvt2_t __attribute__((ext_vector_type(2)));
typedef float float4v __attribute__((ext_vector_type(4)));

struct CellW { const float *Wih, *Whh, *bih, *bhh; };
struct Params { CellW c[6]; const float* y; float* hout; };

__device__ __forceinline__ float fexp2(float x) { return __builtin_amdgcn_exp2f(x); }
__device__ __forceinline__ float frcp(float x)  { return __builtin_amdgcn_rcpf(x); }
__device__ __forceinline__ int packh(float a, float b) {
    cvt2_t p = __builtin_amdgcn_cvt_pkrtz(a, b);
    return __builtin_bit_cast(int, p);
}
__device__ __forceinline__ h4 mk(int lo, int hi) {
    int2 v; v.x = lo; v.y = hi;
    return __builtin_bit_cast(h4, v);
}

// K=16 MFMA: A[m][k],B[k][n] lane(n,Q) holds k=4Q..4Q+3; D lane(n,Q) reg r =
// row 4Q+r, col n. B-layout == D-layout -> recurrence needs only 2 packs.
#define MFMA16(a, b, c) __builtin_amdgcn_mfma_f32_16x16x16f16(a, b, c, 0, 0, 0)

// Paired-rcp LSTM activation: 5 exp + 3 rcp. pi,pf,po pre-scaled by -log2e,
// pg by -2log2e (folded into A/bias). Only ec needs a clamp (inf*0 hazard in
// the paired form); other preacts are bounded (|pre| < ~14).
__device__ __forceinline__ float act_one(float pi, float pf, float pg, float po,
                                         float& c) {
    float ei = fexp2(pi);
    float ef = fexp2(pf);
    float eg = fexp2(pg);
    float f  = frcp(1.f + ef);
    float ig = (1.f - eg) * frcp((1.f + ei) * (1.f + eg));
    float cn = fmaf(f, c, ig);
    c = cn;
    float eo = fexp2(po);
    float ec = fexp2(fminf(cn * -2.8853900817779268f, 80.f));
    return (1.f - ec) * frcp((1.f + eo) * (1.f + ec));
}

// Block = 3 waves = 3 layers of one 16-chain tile, skewed by 1 round.
// Cross-layer h: verbatim per-lane int2 copy via parity LDS slabs.
// Own recurrence: in-register (B-layout == D-layout). x: registers only.
__global__ void __launch_bounds__(192)
__attribute__((amdgpu_waves_per_eu(1, 2)))
lstm_chain_kernel(Params p)
{
    __shared__ int2 lds_h[2][2][SPR][64];   // [producer][parity][k][lane] 16KB

    const int w = threadIdx.x >> 6;     // wave = layer
    const int L = threadIdx.x & 63;
    const int n = L & 15;               // batch col
    const int Q = L >> 4;

    const int tid = blockIdx.x;
    const int dir = tid & 1;
    const int b0  = (tid >> 1) * 16;

    const CellW cw = p.c[dir * 3 + w];
    const float LOG2E = 1.4426950408889634f;

    // ---- A-frags (m=n, k=4Q..4Q+3) + bias, activation scale folded ----
    h4 Aih[4], Ahh[4];
    float4v bs[4];
#pragma unroll
    for (int g = 0; g < 4; ++g) {
        const float s = (g == 2) ? -2.f * LOG2E : -LOG2E;
        const int row = g * 16 + n;
        float vi[4], vh[4];
#pragma unroll
        for (int i = 0; i < 4; ++i) {
            const int k = 4 * Q + i;
            vi[i] = (w == 0) ? ((Q == 0) ? cw.Wih[row * D_IN + k] : 0.f)
                             : cw.Wih[row * 16 + k];
            vh[i] = cw.Whh[row * 16 + k];
        }
        Aih[g] = mk(packh(vi[0] * s, vi[1] * s), packh(vi[2] * s, vi[3] * s));
        Ahh[g] = mk(packh(vh[0] * s, vh[1] * s), packh(vh[2] * s, vh[3] * s));
        const int u0 = g * 16 + 4 * Q;   // bias: reg r -> unit 4Q+r
        float4 bi = *(const float4*)&cw.bih[u0];
        float4 bh = *(const float4*)&cw.bhh[u0];
        bs[g] = (float4v){(bi.x+bh.x)*s, (bi.y+bh.y)*s, (bi.z+bh.z)*s, (bi.w+bh.w)*s};
    }

    // ---- x prefetch (wave 0, lanes L<16 = chain n); fed straight into B ----
    const float* ybase = p.y + (size_t)b0 * (T_LEN * D_IN);
    float4 xn[SPR];
    if (w == 0 && L < 16) {
#pragma unroll
        for (int k = 0; k < SPR; ++k) {
            const int tt = dir ? (T_LEN - 1 - k) : k;
            xn[k] = *(const float4*)(ybase + ((size_t)n * T_LEN + tt) * D_IN);
        }
    }

    float cc[4] = {0.f, 0.f, 0.f, 0.f};
    float h[4] = {0.f, 0.f, 0.f, 0.f};
    int hp0 = 0, hp1 = 0;               // packed own h (the B operand verbatim)

#pragma unroll 1
    for (int s = 0; s < NROUND; ++s) {
        __syncthreads();
        const int t0 = (s - w) * SPR;
        if (t0 < 0 || t0 >= T_LEN) continue;

        // wave 0: commit prefetched x to packed B-dwords, start next loads
        int xp[SPR][2];
        if (w == 0) {
            if (L < 16) {
#pragma unroll
                for (int k = 0; k < SPR; ++k) {
                    xp[k][0] = packh(xn[k].x, xn[k].y);
                    xp[k][1] = packh(xn[k].z, xn[k].w);
                }
                if (t0 + SPR < T_LEN) {
#pragma unroll
                    for (int k = 0; k < SPR; ++k) {
                        const int t = t0 + SPR + k;
                        const int tt = dir ? (T_LEN - 1 - t) : t;
                        xn[k] = *(const float4*)(ybase + ((size_t)n * T_LEN + tt) * D_IN);
                    }
                }
            } else {
#pragma unroll
                for (int k = 0; k < SPR; ++k) { xp[k][0] = 0; xp[k][1] = 0; }
            }
        }

        // hoist all cross-layer h reads (latency off the chain)
        int2 hv[SPR];
        if (w >= 1) {
#pragma unroll
            for (int k = 0; k < SPR; ++k)
                hv[k] = lds_h[w - 1][(s + 1) & 1][k][L];
        }

#pragma unroll
        for (int k = 0; k < SPR; ++k) {
            h4 bin = (w == 0) ? mk(xp[k][0], xp[k][1]) : mk(hv[k].x, hv[k].y);
            h4 bh  = mk(hp0, hp1);
            float4v pi = MFMA16(Ahh[0], bh, MFMA16(Aih[0], bin, bs[0]));
            float4v pf = MFMA16(Ahh[1], bh, MFMA16(Aih[1], bin, bs[1]));
            float4v pg = MFMA16(Ahh[2], bh, MFMA16(Aih[2], bin, bs[2]));
            float4v po = MFMA16(Ahh[3], bh, MFMA16(Aih[3], bin, bs[3]));
            h[0] = act_one(pi[0], pf[0], pg[0], po[0], cc[0]);
            h[1] = act_one(pi[1], pf[1], pg[1], po[1], cc[1]);
            h[2] = act_one(pi[2], pf[2], pg[2], po[2], cc[2]);
            h[3] = act_one(pi[3], pf[3], pg[3], po[3], cc[3]);
            hp0 = packh(h[0], h[1]);
            hp1 = packh(h[2], h[3]);
            if (w < 2) {
                int2 hw; hw.x = hp0; hw.y = hp1;
                lds_h[w][s & 1][k][L] = hw;
            }
        }
    }

    // wave 2 holds h3(T-1): lane (n,Q) has units 4Q..4Q+3, batch n
    if (w == 2) {
        float4v ho = {h[0], h[1], h[2], h[3]};
        *(float4v*)&p.hout[(size_t)(b0 + n) * 32 + dir * 16 + 4 * Q] = ho;
    }
}

__global__ void out_proj_kernel(const float* __restrict__ ws,
                                const float* __restrict__ Wout,
                                const float* __restrict__ bout,
                                float* __restrict__ out, int B)
{
    int idx = blockIdx.x * blockDim.x + threadIdx.x;
    if (idx >= B * 4) return;
    int b = idx >> 2, o = idx & 3;
    float acc = bout[o];
    const float* h = ws + (size_t)b * 32;
    const float* w = Wout + o * 32;
#pragma unroll
    for (int m = 0; m < 32; ++m) acc = fmaf(h[m], w[m], acc);
    out[idx] = acc;
}

extern "C" void kernel_launch(void* const* d_in, const int* in_sizes, int n_in,
                              void* d_out, int out_size, void* d_ws, size_t ws_size,
                              hipStream_t stream)
{
    const int B = in_sizes[0] / (T_LEN * D_IN); // 4096

    Params p;
    for (int s = 0; s < 6; ++s) {
        p.c[s].Wih = (const float*)d_in[1 + 4 * s];
        p.c[s].Whh = (const float*)d_in[2 + 4 * s];
        p.c[s].bih = (const float*)d_in[3 + 4 * s];
        p.c[s].bhh = (const float*)d_in[4 + 4 * s];
    }
    p.y = (const float*)d_in[0];
    p.hout = (float*)d_ws;

    const int tiles = (B / 16) * 2;          // 16 chains per tile, both dirs
    lstm_chain_kernel<<<tiles, 192, 0, stream>>>(p);

    const float* Wout = (const float*)d_in[25];
    const float* bout = (const float*)d_in[26];
    out_proj_kernel<<<(B * 4 + 255) / 256, 256, 0, stream>>>(
        (const float*)d_ws, Wout, bout, (float*)d_out, B);
}